// Round 9
// baseline (639.277 us; speedup 1.0000x reference)
//
#include <hip/hip_runtime.h>
#include <stdint.h>

#define T_STEPS 100
#define BATCH   256
#define NIN     784
#define NHID    512
#define NOUT    10

// ===========================================================================
// NUMERICS CONTRACT (validated PASS R5/R6/R7/R12/R14/R15/R16 — do not break):
//   * gemm1: per C element, fp32 single-accumulator fmaf chain, k ascending,
//     OpenBLAS kc=384 panel folds: cur1 = ((P1 + P2) + P3) + bias, each +
//     a single __fadd_rn:
//       gemm1_dual z=0: C1 = acc(k 0..383)      (pure write, mem1 region)
//       gemm1_dual z=1: C2 = acc(k 384..767)    (pure write, d_ws scratch)
//       leaky_hidden_fused: cur = fadd(fadd(fadd(C1,C2),acc3),b1), where
//         acc3 = 16-k ascending fmaf chain (k 768..783) computed in-register.
//   * gemm2: f64 accumulation of fp32 products, +b2 in f64, single rounding.
//   * recurrences: fp32 _rn ops, ((0.95*mem + cur) - rst), no contraction;
//     spike/reset = (mem > 1.0f).
// PERF JOURNAL:
//   * R5-R8: see git history. R8 582us: AGPR-clean acc (VGPR 56) BK=8 8x8.
//   * R9 645us REGRESSION: tail in GEMM epilogue -> VGPR 204. LESSON:
//     never touch acc non-trivially in the GEMM epilogue.
//   * R12 542.8us: z=2 dual-panel (265.7us), P2 in d_ws, tail in leaky.
//   * R13 617us REGRESSION: BK=16 staging -> VGPR 176. LESSON: keep the
//     unroll window at 8 kk; minimal staging regs.
//   * R14 495.2us: leaky v2 (LDS X-tail, acc3 pipelined, static ring).
//   * R15 482.9us: ring16 + leaky_out reg-preload (-12us; 1-thread-per-chain
//     is latency-bound regardless of ring depth).
//   * R16 468.9us: leaky v4 producer/consumer wave split (-14us). gemm1
//     261us (VALUBusy 64% == FMA 2560cy / LDS 4000cy per-CU -> LDS-BW
//     bound at 1 B/FMA). Remainder 208us vs ~60 floor; gemm2 w2s has a
//     10-way LDS bank conflict (row stride 2048B % 128 == 0).
//   * R17: (a) gemm1 micro 16x8 as TWO 8x8 row-chunks (tm, tm+64), BM=256:
//     LDS 0.75 B/FMA, barrier count halved, keeps stride-8 2-way-free
//     reads + BK=8 window + AGPR-clean acc (predict 195-215us; if VGPR
//     blows >180, revert to R12 gemm1). (b) gemm2 w2s padded [10][516]
//     (stride 2064B % 128 = 16B -> ~conflict-free). Both bit-exact.
// ===========================================================================

// ---------------------------------------------------------------------------
// GEMM1 dual-panel kernel: z=0 -> k 0..383 into C1; z=1 -> k 384..767 into
// C2. BM=256, BN=128, BK=8, 256 threads = 4 waves in 2x2; each wave 8x8
// lanes; micro = 2x(8x8) row-chunks at tm and tm+64. Double-buffered LDS,
// one barrier per iteration, prefetch-ahead. Pure overwrite epilogue.
// ---------------------------------------------------------------------------
#define BM 256
#define BN 128
#define BK 8
#define PANEL_K 384

__global__ __launch_bounds__(256) void gemm1_dual(
    const float* __restrict__ X, const float* __restrict__ W,
    float* __restrict__ C1, float* __restrict__ C2)
{
    __shared__ float As[2][BK][BM + 4];   // 2 x 8320 B
    __shared__ float Bs[2][BK][BN + 4];   // 2 x 4224 B

    const int tid = threadIdx.x;
    const int bm  = blockIdx.x * BM;
    const int bn  = blockIdx.y * BN;
    const int kb  = blockIdx.z ? PANEL_K : 0;
    float* __restrict__ C = blockIdx.z ? C2 : C1;

    // A staging: row = tid (0..255), two contiguous float4 (k 0..7)
    // B staging: rowB = tid>>1 (0..127), koffB = (tid&1)*4
    const int rowB  = tid >> 1;
    const int koffB = (tid & 1) * 4;

    // compute mapping: wave 2x2, lane 8x8; row-chunks at tm and tm+64
    const int w    = tid >> 6;
    const int lane = tid & 63;
    const int tm   = (w & 1) * 128 + (lane & 7) * 8;   // 0..56 / 128..184
    const int tn   = (w >> 1) * 64 + (lane >> 3) * 8;  // 0..120

    float acc[2][8][8];
    #pragma unroll
    for (int h = 0; h < 2; ++h)
        #pragma unroll
        for (int i = 0; i < 8; ++i)
            #pragma unroll
            for (int j = 0; j < 8; ++j) acc[h][i][j] = 0.f;

    const float* Xp = X + (size_t)(bm + tid) * NIN + kb;
    const float* Wp = W + (size_t)(bn + rowB) * NIN + kb + koffB;

    // prologue: stage iter 0 into buffer 0
    float4 pa0 = *(const float4*)(Xp);
    float4 pa1 = *(const float4*)(Xp + 4);
    float4 pb  = *(const float4*)(Wp);
    As[0][0][tid] = pa0.x; As[0][1][tid] = pa0.y;
    As[0][2][tid] = pa0.z; As[0][3][tid] = pa0.w;
    As[0][4][tid] = pa1.x; As[0][5][tid] = pa1.y;
    As[0][6][tid] = pa1.z; As[0][7][tid] = pa1.w;
    Bs[0][koffB+0][rowB] = pb.x; Bs[0][koffB+1][rowB] = pb.y;
    Bs[0][koffB+2][rowB] = pb.z; Bs[0][koffB+3][rowB] = pb.w;

    const int NITER = PANEL_K / BK;   // 48
    for (int it = 0; it < NITER; ++it) {
        const int cur = it & 1;
        __syncthreads();

        if (it + 1 < NITER) {
            const int k0 = (it + 1) * BK;
            pa0 = *(const float4*)(Xp + k0);
            pa1 = *(const float4*)(Xp + k0 + 4);
            pb  = *(const float4*)(Wp + k0);
        }

        #pragma unroll
        for (int kk = 0; kk < BK; ++kk) {   // k ascending
            float4 av0 = *(const float4*)&As[cur][kk][tm];
            float4 av1 = *(const float4*)&As[cur][kk][tm + 4];
            float4 av2 = *(const float4*)&As[cur][kk][tm + 64];
            float4 av3 = *(const float4*)&As[cur][kk][tm + 68];
            float4 bv0 = *(const float4*)&Bs[cur][kk][tn];
            float4 bv1 = *(const float4*)&Bs[cur][kk][tn + 4];
            float a0[8] = {av0.x, av0.y, av0.z, av0.w, av1.x, av1.y, av1.z, av1.w};
            float a1[8] = {av2.x, av2.y, av2.z, av2.w, av3.x, av3.y, av3.z, av3.w};
            float b [8] = {bv0.x, bv0.y, bv0.z, bv0.w, bv1.x, bv1.y, bv1.z, bv1.w};
            #pragma unroll
            for (int i = 0; i < 8; ++i)
                #pragma unroll
                for (int j = 0; j < 8; ++j) {
                    acc[0][i][j] = fmaf(a0[i], b[j], acc[0][i][j]);
                    acc[1][i][j] = fmaf(a1[i], b[j], acc[1][i][j]);
                }
        }

        if (it + 1 < NITER) {
            const int nxt = cur ^ 1;
            As[nxt][0][tid] = pa0.x; As[nxt][1][tid] = pa0.y;
            As[nxt][2][tid] = pa0.z; As[nxt][3][tid] = pa0.w;
            As[nxt][4][tid] = pa1.x; As[nxt][5][tid] = pa1.y;
            As[nxt][6][tid] = pa1.z; As[nxt][7][tid] = pa1.w;
            Bs[nxt][koffB+0][rowB] = pb.x; Bs[nxt][koffB+1][rowB] = pb.y;
            Bs[nxt][koffB+2][rowB] = pb.z; Bs[nxt][koffB+3][rowB] = pb.w;
        }
    }

    #pragma unroll
    for (int h = 0; h < 2; ++h)
        #pragma unroll
        for (int i = 0; i < 8; ++i) {
            size_t r = (size_t)(bm + tm + h * 64 + i) * NHID + bn + tn;
            *(float4*)&C[r]     = make_float4(acc[h][i][0], acc[h][i][1],
                                              acc[h][i][2], acc[h][i][3]);
            *(float4*)&C[r + 4] = make_float4(acc[h][i][4], acc[h][i][5],
                                              acc[h][i][6], acc[h][i][7]);
        }
}

// ---------------------------------------------------------------------------
// Hidden Leaky recurrence, fused with the GEMM1 tail fold (v4):
// producer/consumer wave specialization. Block = 512 threads: tid<256
// consumers (bit-exact chain math), tid>=256 producers stream P1/P2 into an
// LDS double-buffered FIFO in chunks of 8 timesteps. 13 barriers total.
// ---------------------------------------------------------------------------
__global__ __launch_bounds__(512) void leaky_hidden_fused(
    float* __restrict__ mem_io,        // P1 on entry, mem1 on exit
    const float* c2,                   // P2 partial (d_ws; may alias spk_out)
    float* spk_out,
    const float* __restrict__ X,
    const float* __restrict__ W1,
    const float* __restrict__ b1)
{
    __shared__ float4 xs4[T_STEPS][4];    // X[bb][t][768..783], 6.4 KB
    __shared__ float  p1s[2][8][256];     // 8 KB x2
    __shared__ float  p2s[2][8][256];     // 8 KB x2

    const int tid  = threadIdx.x;
    const int lane256 = tid & 255;
    const int base = blockIdx.x * 256;              // chain base
    const size_t STRIDE = (size_t)BATCH * NHID;
    const int bb = base >> 9;                       // batch row (uniform)
    const size_t col = (size_t)base + lane256;      // this thread's chain/col

    // stage X tail (all 512 threads): 400 float4
    {
        const float* xbase = X + (size_t)bb * NIN + 768;
        for (int e = tid; e < T_STEPS * 4; e += 512) {
            const int t = e >> 2, q = e & 3;
            xs4[t][q] = *(const float4*)(xbase + (size_t)t * BATCH * NIN + q * 4);
        }
    }

    const bool producer = (tid >= 256);

    float wt[16];
    float bias = 0.f;
    float mem  = 0.f;

    if (producer) {
        // prologue: chunk 0 (t = 0..7) into buf 0
        float v1[8], v2[8];
        #pragma unroll
        for (int j = 0; j < 8; ++j) {
            v1[j] = mem_io[col + (size_t)j * STRIDE];
            v2[j] = c2[col + (size_t)j * STRIDE];
        }
        #pragma unroll
        for (int j = 0; j < 8; ++j) {
            p1s[0][j][lane256] = v1[j];
            p2s[0][j][lane256] = v2[j];
        }
    } else {
        const int h = (int)(col & (NHID - 1));
        const float* wp = W1 + (size_t)h * NIN + 768;
        float4 w0  = *(const float4*)(wp);
        float4 w1v = *(const float4*)(wp + 4);
        float4 w2v = *(const float4*)(wp + 8);
        float4 w3v = *(const float4*)(wp + 12);
        wt[0]=w0.x;  wt[1]=w0.y;  wt[2]=w0.z;  wt[3]=w0.w;
        wt[4]=w1v.x; wt[5]=w1v.y; wt[6]=w1v.z; wt[7]=w1v.w;
        wt[8]=w2v.x; wt[9]=w2v.y; wt[10]=w2v.z; wt[11]=w2v.w;
        wt[12]=w3v.x; wt[13]=w3v.y; wt[14]=w3v.z; wt[15]=w3v.w;
        bias = b1[h];
    }

    __syncthreads();   // xs4 + chunk 0 ready

    // chunks: c = 0..12; chunk c covers t = 8c .. 8c+nt-1 (nt=4 for c=12)
    for (int c = 0; c <= 12; ++c) {
        if (producer) {
            if (c < 12) {
                const int t0 = (c + 1) * 8;
                const int nb = (c + 1 == 12) ? 4 : 8;
                float v1[8], v2[8];
                #pragma unroll
                for (int j = 0; j < 8; ++j) {
                    if (j < nb) {
                        v1[j] = mem_io[col + (size_t)(t0 + j) * STRIDE];
                        v2[j] = c2[col + (size_t)(t0 + j) * STRIDE];
                    }
                }
                const int pb = (c + 1) & 1;
                #pragma unroll
                for (int j = 0; j < 8; ++j) {
                    if (j < nb) {
                        p1s[pb][j][lane256] = v1[j];
                        p2s[pb][j][lane256] = v2[j];
                    }
                }
            }
        } else {
            const int nt = (c == 12) ? 4 : 8;
            const int cb = c & 1;
            #pragma unroll
            for (int j = 0; j < 8; ++j) {
                if (j < nt) {
                    const int t = c * 8 + j;
                    const float p1 = p1s[cb][j][lane256];
                    const float p2 = p2s[cb][j][lane256];
                    float4 v0 = xs4[t][0], v1 = xs4[t][1];
                    float4 v2 = xs4[t][2], v3 = xs4[t][3];
                    // acc3: 16-k ascending single-accumulator fmaf chain
                    float a = 0.f;
                    a = fmaf(v0.x, wt[0], a);  a = fmaf(v0.y, wt[1], a);
                    a = fmaf(v0.z, wt[2], a);  a = fmaf(v0.w, wt[3], a);
                    a = fmaf(v1.x, wt[4], a);  a = fmaf(v1.y, wt[5], a);
                    a = fmaf(v1.z, wt[6], a);  a = fmaf(v1.w, wt[7], a);
                    a = fmaf(v2.x, wt[8], a);  a = fmaf(v2.y, wt[9], a);
                    a = fmaf(v2.z, wt[10], a); a = fmaf(v2.w, wt[11], a);
                    a = fmaf(v3.x, wt[12], a); a = fmaf(v3.y, wt[13], a);
                    a = fmaf(v3.z, wt[14], a); a = fmaf(v3.w, wt[15], a);

                    const float cur = __fadd_rn(__fadd_rn(__fadd_rn(p1, p2), a), bias);
                    const float rst = (mem > 1.0f) ? 1.0f : 0.0f;
                    mem = __fsub_rn(__fadd_rn(__fmul_rn(0.95f, mem), cur), rst);

                    const size_t off = col + (size_t)t * STRIDE;
                    spk_out[off] = (mem > 1.0f) ? 1.0f : 0.0f;
                    mem_io[off]  = mem;
                }
            }
        }
        __syncthreads();
    }
}

// ---------------------------------------------------------------------------
// GEMM2: cur2[m][o] = fl32( f64( sum_k spk1[m][k]*W2[o][k] + b2[o] ) )
// W2 staged in LDS, rows padded +4 floats (row stride 2064 B % 128 = 16 B)
// so the 10 o-lanes spread across bank-groups (was 10-way conflicted at
// stride 2048). Block = 320 threads = 32 rows x 10 outputs. Bit-exact.
// ---------------------------------------------------------------------------
#define G2_ROWS 32
#define W2PAD  (NHID + 4)

__global__ __launch_bounds__(320) void gemm2_f64(
    const float* __restrict__ spk1, const float* __restrict__ W2,
    const float* __restrict__ b2, float* __restrict__ cur2)
{
    __shared__ float w2s[NOUT][W2PAD];  // 20.6 KB
    const int tid = threadIdx.x;
    for (int i = tid; i < NOUT * NHID; i += 320)
        w2s[i >> 9][i & 511] = W2[i];
    __syncthreads();

    const int r = tid / NOUT;   // 0..31
    const int o = tid % NOUT;   // 0..9
    const size_t m = (size_t)blockIdx.x * G2_ROWS + r;
    const float* rowp = spk1 + m * NHID;
    const float* wp   = &w2s[o][0];
    double dot = 0.0;
    #pragma unroll 4
    for (int k = 0; k < NHID; k += 4) {
        float4 s  = *(const float4*)(rowp + k);
        float4 wv = *(const float4*)(wp + k);
        dot = fma((double)s.x, (double)wv.x, dot);
        dot = fma((double)s.y, (double)wv.y, dot);
        dot = fma((double)s.z, (double)wv.z, dot);
        dot = fma((double)s.w, (double)wv.w, dot);
    }
    cur2[m * NOUT + o] = (float)(dot + (double)b2[o]);   // coalesced
}

// ---------------------------------------------------------------------------
// Output Leaky recurrence (fp32 _rn, v2): one thread per (b,o) chain (2560
// threads = 40 waves). Load ALL 100 cur2 values into registers upfront,
// then run the serial recurrence from registers. Bit-exact.
// ---------------------------------------------------------------------------
__global__ __launch_bounds__(256) void leaky_out_kernel(
    const float* __restrict__ cur2, float* __restrict__ spk2,
    float* __restrict__ mem2)
{
    const int idx = blockIdx.x * blockDim.x + threadIdx.x;
    if (idx >= BATCH * NOUT) return;
    const int STRIDE = BATCH * NOUT;

    float cur[T_STEPS];
    #pragma unroll
    for (int t = 0; t < T_STEPS; ++t)
        cur[t] = cur2[(size_t)t * STRIDE + idx];

    float mem = 0.f;
    #pragma unroll
    for (int t = 0; t < T_STEPS; ++t) {
        const float rst = (mem > 1.0f) ? 1.0f : 0.0f;
        mem = __fsub_rn(__fadd_rn(__fmul_rn(0.95f, mem), cur[t]), rst);
        const size_t off = (size_t)t * STRIDE + idx;
        spk2[off] = (mem > 1.0f) ? 1.0f : 0.0f;
        mem2[off] = mem;
    }
}

// ---------------------------------------------------------------------------
extern "C" void kernel_launch(void* const* d_in, const int* in_sizes, int n_in,
                              void* d_out, int out_size, void* d_ws, size_t ws_size,
                              hipStream_t stream) {
    const float* x  = (const float*)d_in[0];   // (100, 256, 784)
    const float* w1 = (const float*)d_in[1];   // (512, 784)
    const float* b1 = (const float*)d_in[2];   // (512,)
    const float* w2 = (const float*)d_in[3];   // (10, 512)
    const float* b2 = (const float*)d_in[4];   // (10,)

    float* out = (float*)d_out;
    // Output tuple order: (cur2, spk2, spk1, mem2, mem1), each stacked over T.
    float* cur2_out = out;                       // 256000
    float* spk2_out = out + 256000;              // 256000
    float* spk1_out = out + 512000;              // 13107200
    float* mem2_out = out + 13619200;            // 256000
    float* mem1_out = out + 13875200;            // 13107200

    const int M = T_STEPS * BATCH;               // 25600

    // P2 scratch: prefer d_ws (no aliasing); fall back to spk1 region
    // (chunk-disjoint, barrier-ordered aliasing) only if ws too small.
    const size_t p2_bytes = (size_t)M * NHID * sizeof(float);   // 52.4 MB
    float* p2buf = (d_ws != nullptr && ws_size >= p2_bytes)
                       ? (float*)d_ws : spk1_out;

    // 1) P1 -> mem1 region, P2 -> p2buf, one z=2 launch. BM=256 now.
    dim3 gp(M / BM, NHID / BN, 2);               // (100, 4, 2) = 800 blocks
    gemm1_dual<<<gp, 256, 0, stream>>>(x, w1, mem1_out, p2buf);

    // 2) hidden Leaky chains + P3 tail fold + bias (fp32 _rn),
    //    producer/consumer split: 512 blocks x 512 threads.
    leaky_hidden_fused<<<(BATCH * NHID) / 256, 512, 0, stream>>>(
        mem1_out, p2buf, spk1_out, x, w1, b1);

    // 3) cur2 = spk1 @ W2^T + b2 (f64 acc -> fp32)
    gemm2_f64<<<M / G2_ROWS, 320, 0, stream>>>(spk1_out, w2, b2, cur2_out);

    // 4) output Leaky chains (fp32 _rn): cur2 -> (spk2, mem2)
    leaky_out_kernel<<<(BATCH * NOUT + 255) / 256, 256, 0, stream>>>(
        cur2_out, spk2_out, mem2_out);
}

// Round 10
// 452.561 us; speedup vs baseline: 1.4126x; 1.4126x over previous
//
#include <hip/hip_runtime.h>
#include <stdint.h>

#define T_STEPS 100
#define BATCH   256
#define NIN     784
#define NHID    512
#define NOUT    10

// ===========================================================================
// NUMERICS CONTRACT (validated PASS R5/R6/R7/R12/R14/R15/R16 — do not break):
//   * gemm1: per C element, fp32 single-accumulator fmaf chain, k ascending,
//     OpenBLAS kc=384 panel folds: cur1 = ((P1 + P2) + P3) + bias, each +
//     a single __fadd_rn:
//       gemm1_dual z=0: C1 = acc(k 0..383)      (pure write, mem1 region)
//       gemm1_dual z=1: C2 = acc(k 384..767)    (pure write, d_ws scratch)
//       leaky_hidden_fused: cur = fadd(fadd(fadd(C1,C2),acc3),b1), where
//         acc3 = 16-k ascending fmaf chain (k 768..783) computed in-register.
//   * gemm2: f64 accumulation of fp32 products, +b2 in f64, single rounding.
//   * recurrences: fp32 _rn ops, ((0.95*mem + cur) - rst), no contraction;
//     spike/reset = (mem > 1.0f).
// PERF JOURNAL:
//   * R8 582us: AGPR-clean acc (VGPR 56) BK=8 8x8 micro.
//   * R9 645us REGRESSION: tail in GEMM epilogue -> VGPR 204.
//   * R12 542.8us: z=2 dual-panel (261-266us), P2 in d_ws, tail in leaky.
//   * R13 617us REGRESSION: BK=16 staging -> VGPR 176.
//   * R14 495.2us: leaky v2. R15 482.9us: ring16 + leaky_out reg-preload.
//   * R16 468.9us: leaky v4 producer/consumer split. gemm1 261us pinned.
//   * R17 639us REGRESSION: 16x8 micro (acc[2][8][8]) -> VGPR 200 + AGPRs,
//     occ 9.4%, gemm1 491us. REGISTER-CLIFF LAW (R9/R13/R17): the R12
//     shape — acc[8][8], BK=8, 1 float4/matrix staging, untouched
//     epilogue — is the unique AGPR-clean point. Any acc/staging growth
//     forfeits it. gemm1 261us accepted as this structure's floor
//     (LDS-pipe bound 1.5x: 192cy LDS vs 128cy FMA per CU per kk).
//   * R18: revert gemm1 to R12 bytes; keep leaky v4 + leaky_out v2; keep
//     gemm2 W2 pad [10][516] (stride 2064B % 128 = 16 -> o-lanes spread,
//     was 10-way conflicted). Isolates the gemm2 delta vs R16.
// ===========================================================================

// ---------------------------------------------------------------------------
// GEMM1 dual-panel kernel: z=0 -> k 0..383 into C1; z=1 -> k 384..767 into
// C2. BM=BN=128, BK=8, 256 threads = 4 waves in 2x2; each wave 8x8 lanes;
// micro 8x8. Double-buffered LDS, one barrier per iteration, prefetch-ahead.
// Pure overwrite, epilogue untouched (keeps acc in AGPRs, VGPR ~56).
// DO NOT MODIFY (register-cliff law, R9/R13/R17).
// ---------------------------------------------------------------------------
#define BM 128
#define BN 128
#define BK 8
#define PANEL_K 384

__global__ __launch_bounds__(256) void gemm1_dual(
    const float* __restrict__ X, const float* __restrict__ W,
    float* __restrict__ C1, float* __restrict__ C2)
{
    __shared__ float As[2][BK][BM + 4];   // 2 x 4224 B
    __shared__ float Bs[2][BK][BN + 4];   // 2 x 4224 B

    const int tid = threadIdx.x;
    const int bm  = blockIdx.x * BM;
    const int bn  = blockIdx.y * BN;
    const int kb  = blockIdx.z ? PANEL_K : 0;
    float* __restrict__ C = blockIdx.z ? C2 : C1;

    // staging: 128 rows x 8 k = 256 float4
    const int row  = tid >> 1;           // 0..127
    const int koff = (tid & 1) * 4;      // 0 or 4

    // compute mapping: wave 2x2, lane 8x8, micro 8x8
    const int w    = tid >> 6;
    const int lane = tid & 63;
    const int tm   = (w & 1) * 64 + (lane & 7) * 8;    // 0..120
    const int tn   = (w >> 1) * 64 + (lane >> 3) * 8;  // 0..120

    float acc[8][8];
    #pragma unroll
    for (int i = 0; i < 8; ++i)
        #pragma unroll
        for (int j = 0; j < 8; ++j) acc[i][j] = 0.f;

    const float* Xp = X + (size_t)(bm + row) * NIN + kb + koff;
    const float* Wp = W + (size_t)(bn + row) * NIN + kb + koff;

    // prologue: stage iter 0 into buffer 0
    float4 pa = *(const float4*)(Xp);
    float4 pb = *(const float4*)(Wp);
    As[0][koff+0][row] = pa.x; As[0][koff+1][row] = pa.y;
    As[0][koff+2][row] = pa.z; As[0][koff+3][row] = pa.w;
    Bs[0][koff+0][row] = pb.x; Bs[0][koff+1][row] = pb.y;
    Bs[0][koff+2][row] = pb.z; Bs[0][koff+3][row] = pb.w;

    const int NITER = PANEL_K / BK;   // 48
    for (int it = 0; it < NITER; ++it) {
        const int cur = it & 1;
        __syncthreads();

        if (it + 1 < NITER) {
            const int k0 = (it + 1) * BK;
            pa = *(const float4*)(Xp + k0);
            pb = *(const float4*)(Wp + k0);
        }

        #pragma unroll
        for (int kk = 0; kk < BK; ++kk) {   // k ascending
            float4 av0 = *(const float4*)&As[cur][kk][tm];
            float4 av1 = *(const float4*)&As[cur][kk][tm + 4];
            float4 bv0 = *(const float4*)&Bs[cur][kk][tn];
            float4 bv1 = *(const float4*)&Bs[cur][kk][tn + 4];
            float a[8] = {av0.x, av0.y, av0.z, av0.w, av1.x, av1.y, av1.z, av1.w};
            float b[8] = {bv0.x, bv0.y, bv0.z, bv0.w, bv1.x, bv1.y, bv1.z, bv1.w};
            #pragma unroll
            for (int i = 0; i < 8; ++i)
                #pragma unroll
                for (int j = 0; j < 8; ++j)
                    acc[i][j] = fmaf(a[i], b[j], acc[i][j]);
        }

        if (it + 1 < NITER) {
            const int nxt = cur ^ 1;
            As[nxt][koff+0][row] = pa.x; As[nxt][koff+1][row] = pa.y;
            As[nxt][koff+2][row] = pa.z; As[nxt][koff+3][row] = pa.w;
            Bs[nxt][koff+0][row] = pb.x; Bs[nxt][koff+1][row] = pb.y;
            Bs[nxt][koff+2][row] = pb.z; Bs[nxt][koff+3][row] = pb.w;
        }
    }

    #pragma unroll
    for (int i = 0; i < 8; ++i) {
        size_t r = (size_t)(bm + tm + i) * NHID + bn + tn;
        *(float4*)&C[r]     = make_float4(acc[i][0], acc[i][1], acc[i][2], acc[i][3]);
        *(float4*)&C[r + 4] = make_float4(acc[i][4], acc[i][5], acc[i][6], acc[i][7]);
    }
}

// ---------------------------------------------------------------------------
// Hidden Leaky recurrence, fused with the GEMM1 tail fold (v4):
// producer/consumer wave specialization. Block = 512 threads: tid<256
// consumers (bit-exact chain math), tid>=256 producers stream P1/P2 into an
// LDS double-buffered FIFO in chunks of 8 timesteps. 13 barriers total.
// ---------------------------------------------------------------------------
__global__ __launch_bounds__(512) void leaky_hidden_fused(
    float* __restrict__ mem_io,        // P1 on entry, mem1 on exit
    const float* c2,                   // P2 partial (d_ws; may alias spk_out)
    float* spk_out,
    const float* __restrict__ X,
    const float* __restrict__ W1,
    const float* __restrict__ b1)
{
    __shared__ float4 xs4[T_STEPS][4];    // X[bb][t][768..783], 6.4 KB
    __shared__ float  p1s[2][8][256];     // 8 KB x2
    __shared__ float  p2s[2][8][256];     // 8 KB x2

    const int tid  = threadIdx.x;
    const int lane256 = tid & 255;
    const int base = blockIdx.x * 256;              // chain base
    const size_t STRIDE = (size_t)BATCH * NHID;
    const int bb = base >> 9;                       // batch row (uniform)
    const size_t col = (size_t)base + lane256;      // this thread's chain/col

    // stage X tail (all 512 threads): 400 float4
    {
        const float* xbase = X + (size_t)bb * NIN + 768;
        for (int e = tid; e < T_STEPS * 4; e += 512) {
            const int t = e >> 2, q = e & 3;
            xs4[t][q] = *(const float4*)(xbase + (size_t)t * BATCH * NIN + q * 4);
        }
    }

    const bool producer = (tid >= 256);

    float wt[16];
    float bias = 0.f;
    float mem  = 0.f;

    if (producer) {
        // prologue: chunk 0 (t = 0..7) into buf 0
        float v1[8], v2[8];
        #pragma unroll
        for (int j = 0; j < 8; ++j) {
            v1[j] = mem_io[col + (size_t)j * STRIDE];
            v2[j] = c2[col + (size_t)j * STRIDE];
        }
        #pragma unroll
        for (int j = 0; j < 8; ++j) {
            p1s[0][j][lane256] = v1[j];
            p2s[0][j][lane256] = v2[j];
        }
    } else {
        const int h = (int)(col & (NHID - 1));
        const float* wp = W1 + (size_t)h * NIN + 768;
        float4 w0  = *(const float4*)(wp);
        float4 w1v = *(const float4*)(wp + 4);
        float4 w2v = *(const float4*)(wp + 8);
        float4 w3v = *(const float4*)(wp + 12);
        wt[0]=w0.x;  wt[1]=w0.y;  wt[2]=w0.z;  wt[3]=w0.w;
        wt[4]=w1v.x; wt[5]=w1v.y; wt[6]=w1v.z; wt[7]=w1v.w;
        wt[8]=w2v.x; wt[9]=w2v.y; wt[10]=w2v.z; wt[11]=w2v.w;
        wt[12]=w3v.x; wt[13]=w3v.y; wt[14]=w3v.z; wt[15]=w3v.w;
        bias = b1[h];
    }

    __syncthreads();   // xs4 + chunk 0 ready

    // chunks: c = 0..12; chunk c covers t = 8c .. 8c+nt-1 (nt=4 for c=12)
    for (int c = 0; c <= 12; ++c) {
        if (producer) {
            if (c < 12) {
                const int t0 = (c + 1) * 8;
                const int nb = (c + 1 == 12) ? 4 : 8;
                float v1[8], v2[8];
                #pragma unroll
                for (int j = 0; j < 8; ++j) {
                    if (j < nb) {
                        v1[j] = mem_io[col + (size_t)(t0 + j) * STRIDE];
                        v2[j] = c2[col + (size_t)(t0 + j) * STRIDE];
                    }
                }
                const int pb = (c + 1) & 1;
                #pragma unroll
                for (int j = 0; j < 8; ++j) {
                    if (j < nb) {
                        p1s[pb][j][lane256] = v1[j];
                        p2s[pb][j][lane256] = v2[j];
                    }
                }
            }
        } else {
            const int nt = (c == 12) ? 4 : 8;
            const int cb = c & 1;
            #pragma unroll
            for (int j = 0; j < 8; ++j) {
                if (j < nt) {
                    const int t = c * 8 + j;
                    const float p1 = p1s[cb][j][lane256];
                    const float p2 = p2s[cb][j][lane256];
                    float4 v0 = xs4[t][0], v1 = xs4[t][1];
                    float4 v2 = xs4[t][2], v3 = xs4[t][3];
                    // acc3: 16-k ascending single-accumulator fmaf chain
                    float a = 0.f;
                    a = fmaf(v0.x, wt[0], a);  a = fmaf(v0.y, wt[1], a);
                    a = fmaf(v0.z, wt[2], a);  a = fmaf(v0.w, wt[3], a);
                    a = fmaf(v1.x, wt[4], a);  a = fmaf(v1.y, wt[5], a);
                    a = fmaf(v1.z, wt[6], a);  a = fmaf(v1.w, wt[7], a);
                    a = fmaf(v2.x, wt[8], a);  a = fmaf(v2.y, wt[9], a);
                    a = fmaf(v2.z, wt[10], a); a = fmaf(v2.w, wt[11], a);
                    a = fmaf(v3.x, wt[12], a); a = fmaf(v3.y, wt[13], a);
                    a = fmaf(v3.z, wt[14], a); a = fmaf(v3.w, wt[15], a);

                    const float cur = __fadd_rn(__fadd_rn(__fadd_rn(p1, p2), a), bias);
                    const float rst = (mem > 1.0f) ? 1.0f : 0.0f;
                    mem = __fsub_rn(__fadd_rn(__fmul_rn(0.95f, mem), cur), rst);

                    const size_t off = col + (size_t)t * STRIDE;
                    spk_out[off] = (mem > 1.0f) ? 1.0f : 0.0f;
                    mem_io[off]  = mem;
                }
            }
        }
        __syncthreads();
    }
}

// ---------------------------------------------------------------------------
// GEMM2: cur2[m][o] = fl32( f64( sum_k spk1[m][k]*W2[o][k] + b2[o] ) )
// W2 staged in LDS, rows padded +4 floats (row stride 2064 B % 128 = 16 B)
// so the 10 o-lanes spread across bank-groups (was 10-way conflicted at
// stride 2048). Block = 320 threads = 32 rows x 10 outputs. Bit-exact.
// ---------------------------------------------------------------------------
#define G2_ROWS 32
#define W2PAD  (NHID + 4)

__global__ __launch_bounds__(320) void gemm2_f64(
    const float* __restrict__ spk1, const float* __restrict__ W2,
    const float* __restrict__ b2, float* __restrict__ cur2)
{
    __shared__ float w2s[NOUT][W2PAD];  // 20.6 KB
    const int tid = threadIdx.x;
    for (int i = tid; i < NOUT * NHID; i += 320)
        w2s[i >> 9][i & 511] = W2[i];
    __syncthreads();

    const int r = tid / NOUT;   // 0..31
    const int o = tid % NOUT;   // 0..9
    const size_t m = (size_t)blockIdx.x * G2_ROWS + r;
    const float* rowp = spk1 + m * NHID;
    const float* wp   = &w2s[o][0];
    double dot = 0.0;
    #pragma unroll 4
    for (int k = 0; k < NHID; k += 4) {
        float4 s  = *(const float4*)(rowp + k);
        float4 wv = *(const float4*)(wp + k);
        dot = fma((double)s.x, (double)wv.x, dot);
        dot = fma((double)s.y, (double)wv.y, dot);
        dot = fma((double)s.z, (double)wv.z, dot);
        dot = fma((double)s.w, (double)wv.w, dot);
    }
    cur2[m * NOUT + o] = (float)(dot + (double)b2[o]);   // coalesced
}

// ---------------------------------------------------------------------------
// Output Leaky recurrence (fp32 _rn, v2): one thread per (b,o) chain (2560
// threads = 40 waves). Load ALL 100 cur2 values into registers upfront,
// then run the serial recurrence from registers. Bit-exact.
// ---------------------------------------------------------------------------
__global__ __launch_bounds__(256) void leaky_out_kernel(
    const float* __restrict__ cur2, float* __restrict__ spk2,
    float* __restrict__ mem2)
{
    const int idx = blockIdx.x * blockDim.x + threadIdx.x;
    if (idx >= BATCH * NOUT) return;
    const int STRIDE = BATCH * NOUT;

    float cur[T_STEPS];
    #pragma unroll
    for (int t = 0; t < T_STEPS; ++t)
        cur[t] = cur2[(size_t)t * STRIDE + idx];

    float mem = 0.f;
    #pragma unroll
    for (int t = 0; t < T_STEPS; ++t) {
        const float rst = (mem > 1.0f) ? 1.0f : 0.0f;
        mem = __fsub_rn(__fadd_rn(__fmul_rn(0.95f, mem), cur[t]), rst);
        const size_t off = (size_t)t * STRIDE + idx;
        spk2[off] = (mem > 1.0f) ? 1.0f : 0.0f;
        mem2[off] = mem;
    }
}

// ---------------------------------------------------------------------------
extern "C" void kernel_launch(void* const* d_in, const int* in_sizes, int n_in,
                              void* d_out, int out_size, void* d_ws, size_t ws_size,
                              hipStream_t stream) {
    const float* x  = (const float*)d_in[0];   // (100, 256, 784)
    const float* w1 = (const float*)d_in[1];   // (512, 784)
    const float* b1 = (const float*)d_in[2];   // (512,)
    const float* w2 = (const float*)d_in[3];   // (10, 512)
    const float* b2 = (const float*)d_in[4];   // (10,)

    float* out = (float*)d_out;
    // Output tuple order: (cur2, spk2, spk1, mem2, mem1), each stacked over T.
    float* cur2_out = out;                       // 256000
    float* spk2_out = out + 256000;              // 256000
    float* spk1_out = out + 512000;              // 13107200
    float* mem2_out = out + 13619200;            // 256000
    float* mem1_out = out + 13875200;            // 13107200

    const int M = T_STEPS * BATCH;               // 25600

    // P2 scratch: prefer d_ws (no aliasing); fall back to spk1 region
    // (chunk-disjoint, barrier-ordered aliasing) only if ws too small.
    const size_t p2_bytes = (size_t)M * NHID * sizeof(float);   // 52.4 MB
    float* p2buf = (d_ws != nullptr && ws_size >= p2_bytes)
                       ? (float*)d_ws : spk1_out;

    // 1) P1 -> mem1 region, P2 -> p2buf, one z=2 launch.
    dim3 gp(M / BM, NHID / BN, 2);               // (200, 4, 2) = 1600 blocks
    gemm1_dual<<<gp, 256, 0, stream>>>(x, w1, mem1_out, p2buf);

    // 2) hidden Leaky chains + P3 tail fold + bias (fp32 _rn),
    //    producer/consumer split: 512 blocks x 512 threads.
    leaky_hidden_fused<<<(BATCH * NHID) / 256, 512, 0, stream>>>(
        mem1_out, p2buf, spk1_out, x, w1, b1);

    // 3) cur2 = spk1 @ W2^T + b2 (f64 acc -> fp32)
    gemm2_f64<<<M / G2_ROWS, 320, 0, stream>>>(spk1_out, w2, b2, cur2_out);

    // 4) output Leaky chains (fp32 _rn): cur2 -> (spk2, mem2)
    leaky_out_kernel<<<(BATCH * NOUT + 255) / 256, 256, 0, stream>>>(
        cur2_out, spk2_out, mem2_out);
}

// Round 11
// 444.169 us; speedup vs baseline: 1.4393x; 1.0189x over previous
//
#include <hip/hip_runtime.h>
#include <stdint.h>

#define T_STEPS 100
#define BATCH   256
#define NIN     784
#define NHID    512
#define NOUT    10

// ===========================================================================
// NUMERICS CONTRACT (validated PASS R5-R18 — do not break):
//   * gemm1: per C element, fp32 single-accumulator fmaf chain, k ascending,
//     OpenBLAS kc=384 panel folds: cur1 = ((P1 + P2) + P3) + bias, each +
//     a single __fadd_rn:
//       gemm1_dual z=0: C1 = acc(k 0..383)      (pure write, mem1 region)
//       gemm1_dual z=1: C2 = acc(k 384..767)    (pure write, d_ws scratch)
//       leaky_hidden_fused: cur = fadd(fadd(fadd(C1,C2),acc3),b1), where
//         acc3 = 16-k ascending fmaf chain (k 768..783) computed in-register.
//   * gemm2: f64 accumulation of fp32 products, +b2 in f64, single rounding.
//   * recurrences: fp32 _rn ops, ((0.95*mem + cur) - rst), no contraction;
//     spike/reset = (mem > 1.0f).
// PERF JOURNAL:
//   * R8 582us: AGPR-clean acc (VGPR 56) BK=8 8x8 micro.
//   * R9/R13/R17 REGRESSIONS -> REGISTER-CLIFF LAW: the R12 gemm1 shape
//     (acc[8][8], BK=8, 1 float4/matrix staging, untouched epilogue) is the
//     unique AGPR-clean point. gemm1 ~265us accepted as structure floor.
//   * R12 542.8us: z=2 dual-panel, P2 in d_ws, tail folded into leaky.
//   * R14 495.2us: leaky v2. R15 482.9us: ring16 + leaky_out reg-preload.
//   * R16 468.9us: leaky v4 producer/consumer split (256+256).
//   * R18 452.6us: gemm1 reverted + gemm2 W2 pad [10][516] (-16us, 10-way
//     LDS conflict killed). Remainder ~187us vs ~60 floor; models pin the
//     slack on leaky_hidden's 1KB-segment/512KB-stride HBM pattern.
//   * R19: leaky v5 — 256 blocks x 1024 thr (512 consumers + 512 producers);
//     block owns one full batch row -> every stream access is a 2KB
//     contiguous segment (2x R16). LDS 70.4KB (FIFO [2][8][512] x2 + xs4).
//     Math chains verbatim -> bit-exact. If neutral: segment hypothesis
//     dead, R20 fuses gemm2+leaky_out into the block (full hidden vector
//     per (t,b) now block-local).
// ===========================================================================

// ---------------------------------------------------------------------------
// GEMM1 dual-panel kernel: z=0 -> k 0..383 into C1; z=1 -> k 384..767 into
// C2. BM=BN=128, BK=8, 256 threads = 4 waves in 2x2; each wave 8x8 lanes;
// micro 8x8. Double-buffered LDS, one barrier per iteration, prefetch-ahead.
// Pure overwrite, epilogue untouched (keeps acc in AGPRs, VGPR ~56).
// DO NOT MODIFY (register-cliff law, R9/R13/R17).
// ---------------------------------------------------------------------------
#define BM 128
#define BN 128
#define BK 8
#define PANEL_K 384

__global__ __launch_bounds__(256) void gemm1_dual(
    const float* __restrict__ X, const float* __restrict__ W,
    float* __restrict__ C1, float* __restrict__ C2)
{
    __shared__ float As[2][BK][BM + 4];   // 2 x 4224 B
    __shared__ float Bs[2][BK][BN + 4];   // 2 x 4224 B

    const int tid = threadIdx.x;
    const int bm  = blockIdx.x * BM;
    const int bn  = blockIdx.y * BN;
    const int kb  = blockIdx.z ? PANEL_K : 0;
    float* __restrict__ C = blockIdx.z ? C2 : C1;

    // staging: 128 rows x 8 k = 256 float4
    const int row  = tid >> 1;           // 0..127
    const int koff = (tid & 1) * 4;      // 0 or 4

    // compute mapping: wave 2x2, lane 8x8, micro 8x8
    const int w    = tid >> 6;
    const int lane = tid & 63;
    const int tm   = (w & 1) * 64 + (lane & 7) * 8;    // 0..120
    const int tn   = (w >> 1) * 64 + (lane >> 3) * 8;  // 0..120

    float acc[8][8];
    #pragma unroll
    for (int i = 0; i < 8; ++i)
        #pragma unroll
        for (int j = 0; j < 8; ++j) acc[i][j] = 0.f;

    const float* Xp = X + (size_t)(bm + row) * NIN + kb + koff;
    const float* Wp = W + (size_t)(bn + row) * NIN + kb + koff;

    // prologue: stage iter 0 into buffer 0
    float4 pa = *(const float4*)(Xp);
    float4 pb = *(const float4*)(Wp);
    As[0][koff+0][row] = pa.x; As[0][koff+1][row] = pa.y;
    As[0][koff+2][row] = pa.z; As[0][koff+3][row] = pa.w;
    Bs[0][koff+0][row] = pb.x; Bs[0][koff+1][row] = pb.y;
    Bs[0][koff+2][row] = pb.z; Bs[0][koff+3][row] = pb.w;

    const int NITER = PANEL_K / BK;   // 48
    for (int it = 0; it < NITER; ++it) {
        const int cur = it & 1;
        __syncthreads();

        if (it + 1 < NITER) {
            const int k0 = (it + 1) * BK;
            pa = *(const float4*)(Xp + k0);
            pb = *(const float4*)(Wp + k0);
        }

        #pragma unroll
        for (int kk = 0; kk < BK; ++kk) {   // k ascending
            float4 av0 = *(const float4*)&As[cur][kk][tm];
            float4 av1 = *(const float4*)&As[cur][kk][tm + 4];
            float4 bv0 = *(const float4*)&Bs[cur][kk][tn];
            float4 bv1 = *(const float4*)&Bs[cur][kk][tn + 4];
            float a[8] = {av0.x, av0.y, av0.z, av0.w, av1.x, av1.y, av1.z, av1.w};
            float b[8] = {bv0.x, bv0.y, bv0.z, bv0.w, bv1.x, bv1.y, bv1.z, bv1.w};
            #pragma unroll
            for (int i = 0; i < 8; ++i)
                #pragma unroll
                for (int j = 0; j < 8; ++j)
                    acc[i][j] = fmaf(a[i], b[j], acc[i][j]);
        }

        if (it + 1 < NITER) {
            const int nxt = cur ^ 1;
            As[nxt][koff+0][row] = pa.x; As[nxt][koff+1][row] = pa.y;
            As[nxt][koff+2][row] = pa.z; As[nxt][koff+3][row] = pa.w;
            Bs[nxt][koff+0][row] = pb.x; Bs[nxt][koff+1][row] = pb.y;
            Bs[nxt][koff+2][row] = pb.z; Bs[nxt][koff+3][row] = pb.w;
        }
    }

    #pragma unroll
    for (int i = 0; i < 8; ++i) {
        size_t r = (size_t)(bm + tm + i) * NHID + bn + tn;
        *(float4*)&C[r]     = make_float4(acc[i][0], acc[i][1], acc[i][2], acc[i][3]);
        *(float4*)&C[r + 4] = make_float4(acc[i][4], acc[i][5], acc[i][6], acc[i][7]);
    }
}

// ---------------------------------------------------------------------------
// Hidden Leaky recurrence, fused with the GEMM1 tail fold (v5):
// producer/consumer wave specialization, FULL-BATCH-ROW blocks.
//   256 blocks x 1024 threads; block bb owns cols [bb*512, bb*512+512) =
//   all h for batch row bb -> every P1/P2/spk/mem access is one 2 KB
//   contiguous segment per (t, stream) (2x the v4 segment size).
//   tid<512: consumers, one (bb,h) chain each, bit-exact math:
//     cur = fadd(fadd(fadd(P1,P2),acc3),b1);
//     mem = fsub(fadd(fmul(0.95,mem),cur),rst).
//   tid>=512: producers stream P1/P2 into LDS dbuf FIFO, chunks of 8 t.
//   LDS: 2x[2][8][512] = 64 KB + xs4 6.4 KB = 70.4 KB -> 1 block/CU,
//   16 waves/CU. 13 barriers. Aliasing safety in ws-fallback unchanged
//   (producers read t-chunks strictly ahead, barrier-ordered, blocks own
//   disjoint columns).
// ---------------------------------------------------------------------------
__global__ __launch_bounds__(1024) void leaky_hidden_fused(
    float* __restrict__ mem_io,        // P1 on entry, mem1 on exit
    const float* c2,                   // P2 partial (d_ws; may alias spk_out)
    float* spk_out,
    const float* __restrict__ X,
    const float* __restrict__ W1,
    const float* __restrict__ b1)
{
    __shared__ float4 xs4[T_STEPS][4];     // X[bb][t][768..783], 6.4 KB
    __shared__ float  p1s[2][8][NHID];     // 32 KB
    __shared__ float  p2s[2][8][NHID];     // 32 KB

    const int tid = threadIdx.x;
    const int bb  = blockIdx.x;                    // batch row 0..255
    const size_t STRIDE = (size_t)BATCH * NHID;
    const size_t base   = (size_t)bb * NHID;

    // stage X tail: 400 float4 (threads 0..399, one each)
    if (tid < T_STEPS * 4) {
        const int t = tid >> 2, q = tid & 3;
        xs4[t][q] = *(const float4*)(X + (size_t)t * BATCH * NIN
                                       + (size_t)bb * NIN + 768 + q * 4);
    }

    const bool producer = (tid >= 512);
    const int  lane     = tid & 511;               // col offset 0..511
    const size_t col    = base + lane;

    float wt[16];
    float bias = 0.f;
    float mem  = 0.f;

    if (producer) {
        // prologue: chunk 0 (t = 0..7) into buf 0
        float v1[8], v2[8];
        #pragma unroll
        for (int j = 0; j < 8; ++j) {
            v1[j] = mem_io[col + (size_t)j * STRIDE];
            v2[j] = c2[col + (size_t)j * STRIDE];
        }
        #pragma unroll
        for (int j = 0; j < 8; ++j) {
            p1s[0][j][lane] = v1[j];
            p2s[0][j][lane] = v2[j];
        }
    } else {
        const int h = lane;                        // 0..511
        const float* wp = W1 + (size_t)h * NIN + 768;
        float4 w0  = *(const float4*)(wp);
        float4 w1v = *(const float4*)(wp + 4);
        float4 w2v = *(const float4*)(wp + 8);
        float4 w3v = *(const float4*)(wp + 12);
        wt[0]=w0.x;  wt[1]=w0.y;  wt[2]=w0.z;  wt[3]=w0.w;
        wt[4]=w1v.x; wt[5]=w1v.y; wt[6]=w1v.z; wt[7]=w1v.w;
        wt[8]=w2v.x; wt[9]=w2v.y; wt[10]=w2v.z; wt[11]=w2v.w;
        wt[12]=w3v.x; wt[13]=w3v.y; wt[14]=w3v.z; wt[15]=w3v.w;
        bias = b1[h];
    }

    __syncthreads();   // xs4 + chunk 0 ready

    // chunks: c = 0..12; chunk c covers t = 8c .. 8c+nt-1 (nt=4 for c=12)
    for (int c = 0; c <= 12; ++c) {
        if (producer) {
            if (c < 12) {
                const int t0 = (c + 1) * 8;
                const int nb = (c + 1 == 12) ? 4 : 8;
                float v1[8], v2[8];
                #pragma unroll
                for (int j = 0; j < 8; ++j) {
                    if (j < nb) {
                        v1[j] = mem_io[col + (size_t)(t0 + j) * STRIDE];
                        v2[j] = c2[col + (size_t)(t0 + j) * STRIDE];
                    }
                }
                const int pb = (c + 1) & 1;
                #pragma unroll
                for (int j = 0; j < 8; ++j) {
                    if (j < nb) {
                        p1s[pb][j][lane] = v1[j];
                        p2s[pb][j][lane] = v2[j];
                    }
                }
            }
        } else {
            const int nt = (c == 12) ? 4 : 8;
            const int cb = c & 1;
            #pragma unroll
            for (int j = 0; j < 8; ++j) {
                if (j < nt) {
                    const int t = c * 8 + j;
                    const float p1 = p1s[cb][j][lane];
                    const float p2 = p2s[cb][j][lane];
                    float4 v0 = xs4[t][0], v1 = xs4[t][1];
                    float4 v2 = xs4[t][2], v3 = xs4[t][3];
                    // acc3: 16-k ascending single-accumulator fmaf chain
                    float a = 0.f;
                    a = fmaf(v0.x, wt[0], a);  a = fmaf(v0.y, wt[1], a);
                    a = fmaf(v0.z, wt[2], a);  a = fmaf(v0.w, wt[3], a);
                    a = fmaf(v1.x, wt[4], a);  a = fmaf(v1.y, wt[5], a);
                    a = fmaf(v1.z, wt[6], a);  a = fmaf(v1.w, wt[7], a);
                    a = fmaf(v2.x, wt[8], a);  a = fmaf(v2.y, wt[9], a);
                    a = fmaf(v2.z, wt[10], a); a = fmaf(v2.w, wt[11], a);
                    a = fmaf(v3.x, wt[12], a); a = fmaf(v3.y, wt[13], a);
                    a = fmaf(v3.z, wt[14], a); a = fmaf(v3.w, wt[15], a);

                    const float cur = __fadd_rn(__fadd_rn(__fadd_rn(p1, p2), a), bias);
                    const float rst = (mem > 1.0f) ? 1.0f : 0.0f;
                    mem = __fsub_rn(__fadd_rn(__fmul_rn(0.95f, mem), cur), rst);

                    const size_t off = col + (size_t)t * STRIDE;
                    spk_out[off] = (mem > 1.0f) ? 1.0f : 0.0f;
                    mem_io[off]  = mem;
                }
            }
        }
        __syncthreads();
    }
}

// ---------------------------------------------------------------------------
// GEMM2: cur2[m][o] = fl32( f64( sum_k spk1[m][k]*W2[o][k] + b2[o] ) )
// W2 staged in LDS, rows padded +4 floats (row stride 2064 B % 128 = 16 B)
// so the 10 o-lanes spread across bank-groups. Block = 320 threads =
// 32 rows x 10 outputs. Bit-exact.
// ---------------------------------------------------------------------------
#define G2_ROWS 32
#define W2PAD  (NHID + 4)

__global__ __launch_bounds__(320) void gemm2_f64(
    const float* __restrict__ spk1, const float* __restrict__ W2,
    const float* __restrict__ b2, float* __restrict__ cur2)
{
    __shared__ float w2s[NOUT][W2PAD];  // 20.6 KB
    const int tid = threadIdx.x;
    for (int i = tid; i < NOUT * NHID; i += 320)
        w2s[i >> 9][i & 511] = W2[i];
    __syncthreads();

    const int r = tid / NOUT;   // 0..31
    const int o = tid % NOUT;   // 0..9
    const size_t m = (size_t)blockIdx.x * G2_ROWS + r;
    const float* rowp = spk1 + m * NHID;
    const float* wp   = &w2s[o][0];
    double dot = 0.0;
    #pragma unroll 4
    for (int k = 0; k < NHID; k += 4) {
        float4 s  = *(const float4*)(rowp + k);
        float4 wv = *(const float4*)(wp + k);
        dot = fma((double)s.x, (double)wv.x, dot);
        dot = fma((double)s.y, (double)wv.y, dot);
        dot = fma((double)s.z, (double)wv.z, dot);
        dot = fma((double)s.w, (double)wv.w, dot);
    }
    cur2[m * NOUT + o] = (float)(dot + (double)b2[o]);   // coalesced
}

// ---------------------------------------------------------------------------
// Output Leaky recurrence (fp32 _rn, v2): one thread per (b,o) chain (2560
// threads = 40 waves). Load ALL 100 cur2 values into registers upfront,
// then run the serial recurrence from registers. Bit-exact.
// ---------------------------------------------------------------------------
__global__ __launch_bounds__(256) void leaky_out_kernel(
    const float* __restrict__ cur2, float* __restrict__ spk2,
    float* __restrict__ mem2)
{
    const int idx = blockIdx.x * blockDim.x + threadIdx.x;
    if (idx >= BATCH * NOUT) return;
    const int STRIDE = BATCH * NOUT;

    float cur[T_STEPS];
    #pragma unroll
    for (int t = 0; t < T_STEPS; ++t)
        cur[t] = cur2[(size_t)t * STRIDE + idx];

    float mem = 0.f;
    #pragma unroll
    for (int t = 0; t < T_STEPS; ++t) {
        const float rst = (mem > 1.0f) ? 1.0f : 0.0f;
        mem = __fsub_rn(__fadd_rn(__fmul_rn(0.95f, mem), cur[t]), rst);
        const size_t off = (size_t)t * STRIDE + idx;
        spk2[off] = (mem > 1.0f) ? 1.0f : 0.0f;
        mem2[off] = mem;
    }
}

// ---------------------------------------------------------------------------
extern "C" void kernel_launch(void* const* d_in, const int* in_sizes, int n_in,
                              void* d_out, int out_size, void* d_ws, size_t ws_size,
                              hipStream_t stream) {
    const float* x  = (const float*)d_in[0];   // (100, 256, 784)
    const float* w1 = (const float*)d_in[1];   // (512, 784)
    const float* b1 = (const float*)d_in[2];   // (512,)
    const float* w2 = (const float*)d_in[3];   // (10, 512)
    const float* b2 = (const float*)d_in[4];   // (10,)

    float* out = (float*)d_out;
    // Output tuple order: (cur2, spk2, spk1, mem2, mem1), each stacked over T.
    float* cur2_out = out;                       // 256000
    float* spk2_out = out + 256000;              // 256000
    float* spk1_out = out + 512000;              // 13107200
    float* mem2_out = out + 13619200;            // 256000
    float* mem1_out = out + 13875200;            // 13107200

    const int M = T_STEPS * BATCH;               // 25600

    // P2 scratch: prefer d_ws (no aliasing); fall back to spk1 region
    // (chunk-disjoint, barrier-ordered aliasing) only if ws too small.
    const size_t p2_bytes = (size_t)M * NHID * sizeof(float);   // 52.4 MB
    float* p2buf = (d_ws != nullptr && ws_size >= p2_bytes)
                       ? (float*)d_ws : spk1_out;

    // 1) P1 -> mem1 region, P2 -> p2buf, one z=2 launch.
    dim3 gp(M / BM, NHID / BN, 2);               // (200, 4, 2) = 1600 blocks
    gemm1_dual<<<gp, 256, 0, stream>>>(x, w1, mem1_out, p2buf);

    // 2) hidden Leaky chains + P3 tail fold + bias (fp32 _rn),
    //    full-batch-row producer/consumer blocks: 256 blocks x 1024 threads.
    leaky_hidden_fused<<<BATCH, 1024, 0, stream>>>(
        mem1_out, p2buf, spk1_out, x, w1, b1);

    // 3) cur2 = spk1 @ W2^T + b2 (f64 acc -> fp32)
    gemm2_f64<<<M / G2_ROWS, 320, 0, stream>>>(spk1_out, w2, b2, cur2_out);

    // 4) output Leaky chains (fp32 _rn): cur2 -> (spk2, mem2)
    leaky_out_kernel<<<(BATCH * NOUT + 255) / 256, 256, 0, stream>>>(
        cur2_out, spk2_out, mem2_out);
}

// Round 12
// 437.035 us; speedup vs baseline: 1.4628x; 1.0163x over previous
//
#include <hip/hip_runtime.h>
#include <stdint.h>

#define T_STEPS 100
#define BATCH   256
#define NIN     784
#define NHID    512
#define NOUT    10

// ===========================================================================
// NUMERICS CONTRACT (validated PASS R5-R19):
//   * gemm1: per C element, fp32 single-accumulator fmaf chain, k ascending,
//     OpenBLAS kc=384 panel folds: cur1 = ((P1 + P2) + P3) + bias, each +
//     a single __fadd_rn (P1/P2 panels, tail acc3 + bias in leaky). BIT-EXACT.
//   * gemm2: f64 accumulation of fp32 products, +b2 in f64, single f32
//     rounding. R20 NOTE: f64 dot order changed from single 512-chain to
//     {8-elem h-ascending lane chains -> 16-lane l-ascending group sums ->
//     4 g-ascending adds} — deterministic, reassociation error ~1ulp-f64,
//     invisible at f32 (margin 0.0625).
//   * recurrences: fp32 _rn ops, ((0.95*mem + cur) - rst), no contraction;
//     spike/reset = (mem > 1.0f). VERBATIM in all kernels.
// PERF JOURNAL:
//   * R8 582us. R9/R13/R17 REGRESSIONS -> REGISTER-CLIFF LAW: gemm1 must
//     keep acc[8][8], BK=8, 1 float4/matrix staging, untouched epilogue
//     (unique AGPR-clean point, VGPR 56). gemm1 ~265us = structure floor
//     (LDS-pipe model: VALUBusy 64% == FMA320/LDS480 per-CU per kk).
//   * R12 542.8: dual-panel z=2, P2 in d_ws. R14 495: leaky v2.
//   * R15 483: ring16 + lout reg-preload. R16 469: leaky v4 prod/cons.
//   * R18 452.6: gemm2 W2 pad (-16us, 10-way LDS conflict).
//   * R19 444.2: leaky v5 full-batch-row blocks (2KB segments, -8us).
//     leaky modeled near per-CU HBM fair-share floor (~35-40us).
//   * R20: gemm2+leaky_out fused into one kernel per batch row b: W2 in
//     REGS (80/lane, no LDS W2 traffic), 8 waves x strided-t f64 dots,
//     one barrier, 10-thread verbatim recurrence. Probes whether gemm2
//     was the hidden cost: drop >25us => yes; neutral => R21 pivots.
// ===========================================================================

// ---------------------------------------------------------------------------
// GEMM1 dual-panel kernel: z=0 -> k 0..383 into C1; z=1 -> k 384..767 into
// C2. BM=BN=128, BK=8, 256 threads = 4 waves in 2x2; each wave 8x8 lanes;
// micro 8x8. Double-buffered LDS, one barrier per iteration, prefetch-ahead.
// Pure overwrite, epilogue untouched (keeps acc in AGPRs, VGPR ~56).
// DO NOT MODIFY (register-cliff law, R9/R13/R17).
// ---------------------------------------------------------------------------
#define BM 128
#define BN 128
#define BK 8
#define PANEL_K 384

__global__ __launch_bounds__(256) void gemm1_dual(
    const float* __restrict__ X, const float* __restrict__ W,
    float* __restrict__ C1, float* __restrict__ C2)
{
    __shared__ float As[2][BK][BM + 4];   // 2 x 4224 B
    __shared__ float Bs[2][BK][BN + 4];   // 2 x 4224 B

    const int tid = threadIdx.x;
    const int bm  = blockIdx.x * BM;
    const int bn  = blockIdx.y * BN;
    const int kb  = blockIdx.z ? PANEL_K : 0;
    float* __restrict__ C = blockIdx.z ? C2 : C1;

    // staging: 128 rows x 8 k = 256 float4
    const int row  = tid >> 1;           // 0..127
    const int koff = (tid & 1) * 4;      // 0 or 4

    // compute mapping: wave 2x2, lane 8x8, micro 8x8
    const int w    = tid >> 6;
    const int lane = tid & 63;
    const int tm   = (w & 1) * 64 + (lane & 7) * 8;    // 0..120
    const int tn   = (w >> 1) * 64 + (lane >> 3) * 8;  // 0..120

    float acc[8][8];
    #pragma unroll
    for (int i = 0; i < 8; ++i)
        #pragma unroll
        for (int j = 0; j < 8; ++j) acc[i][j] = 0.f;

    const float* Xp = X + (size_t)(bm + row) * NIN + kb + koff;
    const float* Wp = W + (size_t)(bn + row) * NIN + kb + koff;

    // prologue: stage iter 0 into buffer 0
    float4 pa = *(const float4*)(Xp);
    float4 pb = *(const float4*)(Wp);
    As[0][koff+0][row] = pa.x; As[0][koff+1][row] = pa.y;
    As[0][koff+2][row] = pa.z; As[0][koff+3][row] = pa.w;
    Bs[0][koff+0][row] = pb.x; Bs[0][koff+1][row] = pb.y;
    Bs[0][koff+2][row] = pb.z; Bs[0][koff+3][row] = pb.w;

    const int NITER = PANEL_K / BK;   // 48
    for (int it = 0; it < NITER; ++it) {
        const int cur = it & 1;
        __syncthreads();

        if (it + 1 < NITER) {
            const int k0 = (it + 1) * BK;
            pa = *(const float4*)(Xp + k0);
            pb = *(const float4*)(Wp + k0);
        }

        #pragma unroll
        for (int kk = 0; kk < BK; ++kk) {   // k ascending
            float4 av0 = *(const float4*)&As[cur][kk][tm];
            float4 av1 = *(const float4*)&As[cur][kk][tm + 4];
            float4 bv0 = *(const float4*)&Bs[cur][kk][tn];
            float4 bv1 = *(const float4*)&Bs[cur][kk][tn + 4];
            float a[8] = {av0.x, av0.y, av0.z, av0.w, av1.x, av1.y, av1.z, av1.w};
            float b[8] = {bv0.x, bv0.y, bv0.z, bv0.w, bv1.x, bv1.y, bv1.z, bv1.w};
            #pragma unroll
            for (int i = 0; i < 8; ++i)
                #pragma unroll
                for (int j = 0; j < 8; ++j)
                    acc[i][j] = fmaf(a[i], b[j], acc[i][j]);
        }

        if (it + 1 < NITER) {
            const int nxt = cur ^ 1;
            As[nxt][koff+0][row] = pa.x; As[nxt][koff+1][row] = pa.y;
            As[nxt][koff+2][row] = pa.z; As[nxt][koff+3][row] = pa.w;
            Bs[nxt][koff+0][row] = pb.x; Bs[nxt][koff+1][row] = pb.y;
            Bs[nxt][koff+2][row] = pb.z; Bs[nxt][koff+3][row] = pb.w;
        }
    }

    #pragma unroll
    for (int i = 0; i < 8; ++i) {
        size_t r = (size_t)(bm + tm + i) * NHID + bn + tn;
        *(float4*)&C[r]     = make_float4(acc[i][0], acc[i][1], acc[i][2], acc[i][3]);
        *(float4*)&C[r + 4] = make_float4(acc[i][4], acc[i][5], acc[i][6], acc[i][7]);
    }
}

// ---------------------------------------------------------------------------
// Hidden Leaky recurrence, fused with the GEMM1 tail fold (v5):
// producer/consumer wave specialization, FULL-BATCH-ROW blocks.
// 256 blocks x 1024 threads; block bb owns all h for batch row bb.
// tid<512: consumers (bit-exact chain math); tid>=512: producers stream
// P1/P2 into LDS dbuf FIFO in chunks of 8 t. See R16/R19 notes.
// ---------------------------------------------------------------------------
__global__ __launch_bounds__(1024) void leaky_hidden_fused(
    float* __restrict__ mem_io,        // P1 on entry, mem1 on exit
    const float* c2,                   // P2 partial (d_ws; may alias spk_out)
    float* spk_out,
    const float* __restrict__ X,
    const float* __restrict__ W1,
    const float* __restrict__ b1)
{
    __shared__ float4 xs4[T_STEPS][4];     // X[bb][t][768..783], 6.4 KB
    __shared__ float  p1s[2][8][NHID];     // 32 KB
    __shared__ float  p2s[2][8][NHID];     // 32 KB

    const int tid = threadIdx.x;
    const int bb  = blockIdx.x;                    // batch row 0..255
    const size_t STRIDE = (size_t)BATCH * NHID;
    const size_t base   = (size_t)bb * NHID;

    // stage X tail: 400 float4 (threads 0..399, one each)
    if (tid < T_STEPS * 4) {
        const int t = tid >> 2, q = tid & 3;
        xs4[t][q] = *(const float4*)(X + (size_t)t * BATCH * NIN
                                       + (size_t)bb * NIN + 768 + q * 4);
    }

    const bool producer = (tid >= 512);
    const int  lane     = tid & 511;               // col offset 0..511
    const size_t col    = base + lane;

    float wt[16];
    float bias = 0.f;
    float mem  = 0.f;

    if (producer) {
        // prologue: chunk 0 (t = 0..7) into buf 0
        float v1[8], v2[8];
        #pragma unroll
        for (int j = 0; j < 8; ++j) {
            v1[j] = mem_io[col + (size_t)j * STRIDE];
            v2[j] = c2[col + (size_t)j * STRIDE];
        }
        #pragma unroll
        for (int j = 0; j < 8; ++j) {
            p1s[0][j][lane] = v1[j];
            p2s[0][j][lane] = v2[j];
        }
    } else {
        const int h = lane;                        // 0..511
        const float* wp = W1 + (size_t)h * NIN + 768;
        float4 w0  = *(const float4*)(wp);
        float4 w1v = *(const float4*)(wp + 4);
        float4 w2v = *(const float4*)(wp + 8);
        float4 w3v = *(const float4*)(wp + 12);
        wt[0]=w0.x;  wt[1]=w0.y;  wt[2]=w0.z;  wt[3]=w0.w;
        wt[4]=w1v.x; wt[5]=w1v.y; wt[6]=w1v.z; wt[7]=w1v.w;
        wt[8]=w2v.x; wt[9]=w2v.y; wt[10]=w2v.z; wt[11]=w2v.w;
        wt[12]=w3v.x; wt[13]=w3v.y; wt[14]=w3v.z; wt[15]=w3v.w;
        bias = b1[h];
    }

    __syncthreads();   // xs4 + chunk 0 ready

    // chunks: c = 0..12; chunk c covers t = 8c .. 8c+nt-1 (nt=4 for c=12)
    for (int c = 0; c <= 12; ++c) {
        if (producer) {
            if (c < 12) {
                const int t0 = (c + 1) * 8;
                const int nb = (c + 1 == 12) ? 4 : 8;
                float v1[8], v2[8];
                #pragma unroll
                for (int j = 0; j < 8; ++j) {
                    if (j < nb) {
                        v1[j] = mem_io[col + (size_t)(t0 + j) * STRIDE];
                        v2[j] = c2[col + (size_t)(t0 + j) * STRIDE];
                    }
                }
                const int pb = (c + 1) & 1;
                #pragma unroll
                for (int j = 0; j < 8; ++j) {
                    if (j < nb) {
                        p1s[pb][j][lane] = v1[j];
                        p2s[pb][j][lane] = v2[j];
                    }
                }
            }
        } else {
            const int nt = (c == 12) ? 4 : 8;
            const int cb = c & 1;
            #pragma unroll
            for (int j = 0; j < 8; ++j) {
                if (j < nt) {
                    const int t = c * 8 + j;
                    const float p1 = p1s[cb][j][lane];
                    const float p2 = p2s[cb][j][lane];
                    float4 v0 = xs4[t][0], v1 = xs4[t][1];
                    float4 v2 = xs4[t][2], v3 = xs4[t][3];
                    // acc3: 16-k ascending single-accumulator fmaf chain
                    float a = 0.f;
                    a = fmaf(v0.x, wt[0], a);  a = fmaf(v0.y, wt[1], a);
                    a = fmaf(v0.z, wt[2], a);  a = fmaf(v0.w, wt[3], a);
                    a = fmaf(v1.x, wt[4], a);  a = fmaf(v1.y, wt[5], a);
                    a = fmaf(v1.z, wt[6], a);  a = fmaf(v1.w, wt[7], a);
                    a = fmaf(v2.x, wt[8], a);  a = fmaf(v2.y, wt[9], a);
                    a = fmaf(v2.z, wt[10], a); a = fmaf(v2.w, wt[11], a);
                    a = fmaf(v3.x, wt[12], a); a = fmaf(v3.y, wt[13], a);
                    a = fmaf(v3.z, wt[14], a); a = fmaf(v3.w, wt[15], a);

                    const float cur = __fadd_rn(__fadd_rn(__fadd_rn(p1, p2), a), bias);
                    const float rst = (mem > 1.0f) ? 1.0f : 0.0f;
                    mem = __fsub_rn(__fadd_rn(__fmul_rn(0.95f, mem), cur), rst);

                    const size_t off = col + (size_t)t * STRIDE;
                    spk_out[off] = (mem > 1.0f) ? 1.0f : 0.0f;
                    mem_io[off]  = mem;
                }
            }
        }
        __syncthreads();
    }
}

// ---------------------------------------------------------------------------
// GEMM2 + output Leaky, fused (R20). One block per batch row b, 512 threads
// = 8 waves. W2 lives in REGISTERS: lane l holds W2[o][8l..8l+7] for all
// o (80 VGPR). Wave w handles t = w, w+8, ... :
//   lanes: 2 coalesced float4 spk1 loads (2 KB/wave), then per o an
//   8-element h-ascending f64 fma chain -> ps[w][l][o].
//   stage2a (40 lanes, o,g): 16-partial l-ascending f64 sum -> ps2.
//   stage2b (10 lanes): 4 g-ascending adds + b2 (f64) -> single f32
//   rounding -> cur2 global + LDS.
// One barrier; threads 0..9 then run the VERBATIM leaky_out recurrence
// from LDS cur2. f64 reassociation only (see contract note).
// ---------------------------------------------------------------------------
__global__ __launch_bounds__(512) void gemm2_lout_fused(
    const float* __restrict__ spk1, const float* __restrict__ W2,
    const float* __restrict__ b2, float* __restrict__ cur2,
    float* __restrict__ spk2, float* __restrict__ mem2)
{
    __shared__ double ps [8][64][10];   // 40 KB: per-wave lane partials
    __shared__ double ps2[8][4][10];    // 2.5 KB: per-wave group sums
    __shared__ float  c2s[T_STEPS][10]; // 4 KB: cur2 cache for recurrence

    const int tid  = threadIdx.x;
    const int w    = tid >> 6;          // wave 0..7
    const int lane = tid & 63;          // 0..63
    const int b    = blockIdx.x;        // batch row

    // W2[o][8l..8l+7] for all o -> 80 regs
    float w2r[10][8];
    #pragma unroll
    for (int o = 0; o < NOUT; ++o) {
        float4 a0 = *(const float4*)(W2 + (size_t)o * NHID + 8 * lane);
        float4 a1 = *(const float4*)(W2 + (size_t)o * NHID + 8 * lane + 4);
        w2r[o][0]=a0.x; w2r[o][1]=a0.y; w2r[o][2]=a0.z; w2r[o][3]=a0.w;
        w2r[o][4]=a1.x; w2r[o][5]=a1.y; w2r[o][6]=a1.z; w2r[o][7]=a1.w;
    }

    for (int t = w; t < T_STEPS; t += 8) {
        // spk1 row slice: 8 floats at h = 8*lane
        const float* sp = spk1 + (size_t)t * (BATCH * NHID)
                               + (size_t)b * NHID + 8 * lane;
        float4 s0 = *(const float4*)(sp);
        float4 s1 = *(const float4*)(sp + 4);
        const float s[8] = {s0.x, s0.y, s0.z, s0.w, s1.x, s1.y, s1.z, s1.w};

        // per-o 8-element h-ascending f64 chains
        #pragma unroll
        for (int o = 0; o < NOUT; ++o) {
            double d = 0.0;
            #pragma unroll
            for (int j = 0; j < 8; ++j)
                d = fma((double)s[j], (double)w2r[o][j], d);
            ps[w][lane][o] = d;
        }
        __builtin_amdgcn_s_waitcnt(0);   // drain LDS writes (wave-local RAW)

        // stage 2a: 40 lanes: (o = lane>>2, g = lane&3): sum 16 partials,
        // l ascending within group
        if (lane < 40) {
            const int o = lane >> 2, g = lane & 3;
            double d = 0.0;
            #pragma unroll
            for (int l2 = 0; l2 < 16; ++l2)
                d += ps[w][g * 16 + l2][o];
            ps2[w][g][o] = d;
        }
        __builtin_amdgcn_s_waitcnt(0);

        // stage 2b: 10 lanes: 4 g-ascending adds + b2 (f64), single rounding
        if (lane < 10) {
            const int o = lane;
            double d = ((ps2[w][0][o] + ps2[w][1][o]) + ps2[w][2][o])
                       + ps2[w][3][o];
            const float c = (float)(d + (double)b2[o]);
            cur2[(size_t)t * (BATCH * NOUT) + (size_t)b * NOUT + o] = c;
            c2s[t][o] = c;
        }
    }

    __syncthreads();   // all cur2 cached

    // output Leaky recurrence: VERBATIM fp32 _rn chain, threads 0..9
    if (tid < NOUT) {
        const int o = tid;
        float mem = 0.f;
        for (int t = 0; t < T_STEPS; ++t) {
            const float cur = c2s[t][o];
            const float rst = (mem > 1.0f) ? 1.0f : 0.0f;
            mem = __fsub_rn(__fadd_rn(__fmul_rn(0.95f, mem), cur), rst);
            const size_t off = (size_t)t * (BATCH * NOUT) + (size_t)b * NOUT + o;
            spk2[off] = (mem > 1.0f) ? 1.0f : 0.0f;
            mem2[off] = mem;
        }
    }
}

// ---------------------------------------------------------------------------
extern "C" void kernel_launch(void* const* d_in, const int* in_sizes, int n_in,
                              void* d_out, int out_size, void* d_ws, size_t ws_size,
                              hipStream_t stream) {
    const float* x  = (const float*)d_in[0];   // (100, 256, 784)
    const float* w1 = (const float*)d_in[1];   // (512, 784)
    const float* b1 = (const float*)d_in[2];   // (512,)
    const float* w2 = (const float*)d_in[3];   // (10, 512)
    const float* b2 = (const float*)d_in[4];   // (10,)

    float* out = (float*)d_out;
    // Output tuple order: (cur2, spk2, spk1, mem2, mem1), each stacked over T.
    float* cur2_out = out;                       // 256000
    float* spk2_out = out + 256000;              // 256000
    float* spk1_out = out + 512000;              // 13107200
    float* mem2_out = out + 13619200;            // 256000
    float* mem1_out = out + 13875200;            // 13107200

    const int M = T_STEPS * BATCH;               // 25600

    // P2 scratch: prefer d_ws (no aliasing); fall back to spk1 region
    // (chunk-disjoint, barrier-ordered aliasing) only if ws too small.
    const size_t p2_bytes = (size_t)M * NHID * sizeof(float);   // 52.4 MB
    float* p2buf = (d_ws != nullptr && ws_size >= p2_bytes)
                       ? (float*)d_ws : spk1_out;

    // 1) P1 -> mem1 region, P2 -> p2buf, one z=2 launch.
    dim3 gp(M / BM, NHID / BN, 2);               // (200, 4, 2) = 1600 blocks
    gemm1_dual<<<gp, 256, 0, stream>>>(x, w1, mem1_out, p2buf);

    // 2) hidden Leaky chains + P3 tail fold + bias (fp32 _rn),
    //    full-batch-row producer/consumer blocks: 256 blocks x 1024 threads.
    leaky_hidden_fused<<<BATCH, 1024, 0, stream>>>(
        mem1_out, p2buf, spk1_out, x, w1, b1);

    // 3) cur2 = spk1 @ W2^T + b2 (f64 acc -> f32) + output Leaky, fused:
    //    one block per batch row.
    gemm2_lout_fused<<<BATCH, 512, 0, stream>>>(
        spk1_out, w2, b2, cur2_out, spk2_out, mem2_out);
}